// Round 1
// baseline (5143.017 us; speedup 1.0000x reference)
//
#include <hip/hip_runtime.h>
#include <math.h>

#define NN 4096
#define INFV 1e30f

// ---------------------------------------------------------------------------
// DP kernel: 64 workgroups x 1 wave (64 lanes). Workgroup g owns columns
// [64g, 64g+64). Lane l = column 64g+l. Anti-diagonal wavefront inside the
// wave: at step t, lane l computes row r = t - l. Dependencies:
//   up   = my previous value            (register `cur`)
//   left = lane l-1's value from t-1    (register `l1s`, via shfl_up)
//   diag = lane l-1's value from t-2    (register `l2s`)
// Lane 0 takes left/diag from the left strip's boundary column, streamed
// through an agent-scope (cross-XCD coherent) global buffer + flags.
// ---------------------------------------------------------------------------
__global__ __launch_bounds__(64) void dtw_dp_kernel(const float* __restrict__ D,
                                                    float* __restrict__ cost_out,
                                                    float* __restrict__ colbuf,
                                                    int* __restrict__ flags) {
    // 128-row LDS ring of E = exp(-D) tile, stride 68 floats:
    // read addr = 68*(t-l) + l -> bank = (4t - 3l) mod 32 -> 2-way only (free)
    __shared__ float ebuf[128 * 68];

    const int g    = blockIdx.x;
    const int lane = threadIdx.x;
    const float* Dg = D + (g << 6);
    const float* colL = colbuf + (size_t)(g - 1) * NN;  // left strip's boundary
    float*       colM = colbuf + (size_t)g * NN;        // my boundary (col 63)

    float cur = INFV, l1s = INFV, l2s = INFV, bprev = INFV, bvals = INFV;

    for (int t = 0; t < NN + 63; ++t) {
        if ((t & 63) == 0) {
            // ---- stage E rows [t, t+64) of my 64 columns into the LDS ring
            // per iteration: 4 rows x 64 cols (lane>>4 = row, lane&15 = col/4)
            #pragma unroll
            for (int it = 0; it < 16; ++it) {
                const int row = t + (lane >> 4) + (it << 2);
                if (row < NN) {
                    const float4 dv = *reinterpret_cast<const float4*>(
                        Dg + (size_t)row * NN + ((lane & 15) << 2));
                    float4 ev;
                    ev.x = __expf(-dv.x);
                    ev.y = __expf(-dv.y);
                    ev.z = __expf(-dv.z);
                    ev.w = __expf(-dv.w);
                    *reinterpret_cast<float4*>(
                        &ebuf[(row & 127) * 68 + ((lane & 15) << 2)]) = ev;
                }
            }
            // ---- fetch next 64 boundary values from the left strip
            if (g > 0) {
                const int needed = (t + 64 < NN) ? (t + 64) : NN;
                if (lane == 0) {
                    while (__hip_atomic_load(flags + (g - 1), __ATOMIC_RELAXED,
                                             __HIP_MEMORY_SCOPE_AGENT) < needed) { }
                }
                asm volatile("" ::: "memory");  // keep loads below the spin
                const int rowb = t + lane;
                bvals = (rowb < NN)
                            ? __hip_atomic_load(colL + rowb, __ATOMIC_RELAXED,
                                                __HIP_MEMORY_SCOPE_AGENT)
                            : INFV;
            }
        }

        const int  r     = t - lane;
        const bool valid = ((unsigned)r < (unsigned)NN);
        // boundary value for lane 0's row (= t): b[t] lives in lane (t & 63)
        const float bcur = (g > 0) ? __shfl(bvals, t & 63) : INFV;

        float Ev = 0.f;
        if (valid) Ev = ebuf[(r & 127) * 68 + lane];

        const float l1 = (lane == 0) ? bcur : l1s;   // c[r][col-1]
        const float l2 = (lane == 0) ? bprev : l2s;  // c[r-1][col-1]
        float m = fminf(cur, fminf(l1, l2));
        if (g == 0 && lane == 0 && t == 0) m = 0.f;  // corner cell (0,0)
        const float v = valid ? (Ev + m) : INFV;
        if (valid) cur = v;

        // ---- publish my boundary column (lane 63) for the right strip
        if (lane == 63 && valid) {
            __hip_atomic_store(colM + r, v, __ATOMIC_RELAXED,
                               __HIP_MEMORY_SCOPE_AGENT);
            if (g == 63 && r == NN - 1) cost_out[0] = v;  // final DTW cost
        }
        // rows 0 .. t-63 are done for lane 63; publish flag every 64 rows
        if (g < 63 && (t & 63) == 62 && t > 62 && lane == 63) {
            __hip_atomic_store(flags + g, t - 62, __ATOMIC_RELEASE,
                               __HIP_MEMORY_SCOPE_AGENT);
        }

        // ---- rotate the diagonal registers
        const float sh = __shfl_up(v, 1);  // lane l gets lane l-1's v (row r)
        l2s = l1s;
        l1s = sh;
        bprev = bcur;
    }
}

// ---------------------------------------------------------------------------
// acc_grad[i,j] = d[i+1,j+1] + d[i+1,j] + d[i,j+1] - d[i,j],  d = exp(-exp(-D))
// with d == 0 outside the matrix (bottom/right zero-pad).
// One thread per 4 outputs; float4 loads; scalar stores (G is 4B-aligned only).
// ---------------------------------------------------------------------------
__device__ __forceinline__ float dfun(float x) {
    return __expf(-__expf(-x));
}

__global__ __launch_bounds__(256) void dtw_grad_kernel(const float* __restrict__ D,
                                                       float* __restrict__ G) {
    const int idx = blockIdx.x * 256 + threadIdx.x;
    const int i = idx >> 10;           // row
    const int j = (idx & 1023) << 2;   // col (multiple of 4)
    if (i >= NN) return;

    const float* row0 = D + (size_t)i * NN + j;
    const bool hasR = (i + 1) < NN;
    const bool hasC = (j + 4) < NN;

    const float4 r0 = *reinterpret_cast<const float4*>(row0);
    float4 r1 = make_float4(0.f, 0.f, 0.f, 0.f);
    if (hasR) r1 = *reinterpret_cast<const float4*>(row0 + NN);
    const float s0 = hasC ? row0[4] : 0.f;
    const float s1 = (hasR && hasC) ? row0[NN + 4] : 0.f;

    const float a0 = dfun(r0.x);
    const float a1 = dfun(r0.y);
    const float a2 = dfun(r0.z);
    const float a3 = dfun(r0.w);
    const float a4 = hasC ? dfun(s0) : 0.f;

    const float b0 = hasR ? dfun(r1.x) : 0.f;
    const float b1 = hasR ? dfun(r1.y) : 0.f;
    const float b2 = hasR ? dfun(r1.z) : 0.f;
    const float b3 = hasR ? dfun(r1.w) : 0.f;
    const float b4 = (hasR && hasC) ? dfun(s1) : 0.f;

    float* go = G + (size_t)i * NN + j;
    go[0] = b1 + b0 + a1 - a0;
    go[1] = b2 + b1 + a2 - a1;
    go[2] = b3 + b2 + a3 - a2;
    go[3] = b4 + b3 + a4 - a3;
}

// ---------------------------------------------------------------------------
extern "C" void kernel_launch(void* const* d_in, const int* in_sizes, int n_in,
                              void* d_out, int out_size, void* d_ws, size_t ws_size,
                              hipStream_t stream) {
    (void)in_sizes; (void)n_in; (void)out_size;
    const float* D = (const float*)d_in[0];
    float* out = (float*)d_out;

    // scratch: 64*4096 boundary floats + 64 flags. Prefer d_ws; fall back to
    // the grad region of d_out (safe: grad kernel rewrites it afterwards,
    // stream-ordered after the DP kernel).
    const size_t need = (size_t)64 * NN * sizeof(float) + 64 * sizeof(int);
    float* colbuf = (ws_size >= need) ? (float*)d_ws : (out + 1);
    int* flags = (int*)(colbuf + (size_t)64 * NN);

    hipMemsetAsync(flags, 0, 64 * sizeof(int), stream);
    dtw_dp_kernel<<<64, 64, 0, stream>>>(D, out, colbuf, flags);
    dtw_grad_kernel<<<dim3((NN * (NN / 4)) / 256), dim3(256), 0, stream>>>(D, out + 1);
}

// Round 2
// 1162.255 us; speedup vs baseline: 4.4250x; 4.4250x over previous
//
#include <hip/hip_runtime.h>
#include <math.h>

#define NN 4096
#define STRIPS 32
#define SW 128                       // strip width (columns per workgroup)
#define RING_ROWS 112                // LDS ring rows (>= 64 window + 32 ahead + 16)
#define RING_BYTES (RING_ROWS * SW * 4)   // 57344 B
#define BATCH 16
#define NSTEPS (NN + 63)             // 4159 wavefront steps; loop runs 4160
#define INFV 1e30f
#define SENTU 0xFFFFFFFFu            // memset(0xFF) sentinel = -NaN, never a DP result

// lane l <- lane l-1 (whole-wave shift right by 1), VALU-latency cross-lane move
__device__ __forceinline__ float dpp_wave_shr1(float x) {
    return __int_as_float(__builtin_amdgcn_update_dpp(
        0, __float_as_int(x), 0x138 /*WAVE_SHR1*/, 0xf, 0xf, false));
}

// lanes 0..15 load boundary rows [row0, row0+16) from the left strip's column
__device__ __forceinline__ float bload(const unsigned* colL, int row, int lane) {
    float v = INFV;
    if (lane < 16 && row < NN) {
        unsigned u = __hip_atomic_load(colL + row, __ATOMIC_RELAXED,
                                       __HIP_MEMORY_SCOPE_AGENT);
        v = __uint_as_float(u);
    }
    return v;
}

// async-stage 16 rows [rb, rb+16) of this strip (128 cols) into the LDS ring.
// One global_load_lds (16B/lane) covers 2 rows: lanes 0-31 row r0, 32-63 row r0+1.
// slotb is rb % RING_ROWS (even; pairs never wrap mid-instruction).
__device__ __forceinline__ void stage16(const float* Dg, float* ring, int rb,
                                        int slotb, int lane) {
    #pragma unroll
    for (int k = 0; k < 8; ++k) {
        const int r0 = rb + 2 * k;
        if (r0 < NN) {
            int slot = slotb + 2 * k;
            if (slot >= RING_ROWS) slot -= RING_ROWS;
            const float* gsrc =
                Dg + (size_t)(r0 + (lane >> 5)) * NN + ((lane & 31) << 2);
            __builtin_amdgcn_global_load_lds(
                (const __attribute__((address_space(1))) unsigned*)gsrc,
                (__attribute__((address_space(3))) unsigned*)((char*)ring +
                                                             slot * (SW * 4)),
                16, 0, 0);
        }
    }
}

// ---------------------------------------------------------------------------
// DP: 32 workgroups x 1 wave. Strip g owns cols [128g, 128g+128); lane l owns
// cols 2l, 2l+1. At step t lane l computes row r = t - l (2 cells). Left/diag
// neighbor values arrive via DPP wave_shr1 (register chain); strip boundary
// values via sentinel-validated agent-scope loads, prefetched 1 batch ahead.
// ---------------------------------------------------------------------------
__global__ __launch_bounds__(64) void dtw_dp(const float* __restrict__ D,
                                             float* __restrict__ cost_out,
                                             unsigned* __restrict__ colbuf) {
    __shared__ float ring[RING_ROWS * SW];

    const int g = blockIdx.x;
    const int lane = threadIdx.x;
    const float* Dg = D + g * SW;
    const unsigned* colLu = colbuf + (size_t)(g - 1) * NN;
    unsigned* colMu = colbuf + (size_t)g * NN;
    const bool lane0 = (lane == 0);
    const bool pub = (lane == 63) && (g < STRIPS - 1);
    const bool last = (g == STRIPS - 1) && (lane == 63);

    // prologue: stage rows [0,32) (2 batches ahead), prefetch boundary [0,16)
    stage16(Dg, ring, 0, 0, lane);
    stage16(Dg, ring, 16, 16, lane);
    float bvn = (g > 0) ? bload(colLu, lane, lane) : INFV;

    float cur0 = INFV, cur1 = INFV;   // c[r-1][2l], c[r-1][2l+1]
    float l1s = INFV, l2s = INFV;     // lane l-1's c1 from t-1, t-2
    float bprev = INFV, bv = INFV;    // boundary regs
    int rl = -lane;                   // my row this step
    int raddr = ((lane == 0) ? 0 : (RING_ROWS - lane)) * (SW * 4) + lane * 8;
    int sstage = 32;                  // ring slot of next stage batch

    for (int tb = 0; tb < NSTEPS + 1; tb += BATCH) {   // 260 batches
        if (g > 0) {
            // validate rows [tb, tb+16) (prefetched last batch); spin if behind
            while (__any((lane < 16) && ((tb + lane) < NN) &&
                         (__float_as_uint(bvn) == SENTU))) {
                bvn = bload(colLu, tb + lane, lane);
            }
            bv = bvn;
            bvn = bload(colLu, tb + BATCH + lane, lane);  // prefetch next
        }
        // rows [tb, tb+16) were staged 2 batches ago; "all but newest 8 vmem
        // retired" always covers that batch (in-order vmcnt retirement).
        asm volatile("s_waitcnt vmcnt(8)" ::: "memory");
        stage16(Dg, ring, tb + 32, sstage, lane);
        sstage += BATCH; if (sstage >= RING_ROWS) sstage -= RING_ROWS;

        #pragma unroll
        for (int s = 0; s < BATCH; ++s) {
            const float2 dv = *reinterpret_cast<const float2*>(
                reinterpret_cast<const char*>(ring) + raddr);
            const float e0 = __expf(-dv.x);
            const float e1 = __expf(-dv.y);
            float bcur = INFV;
            if (g > 0)
                bcur = __int_as_float(
                    __builtin_amdgcn_readlane(__float_as_int(bv), s));
            const bool r0row = (rl == 0);
            const float L1 = lane0 ? bcur : l1s;   // c[r][col-1]
            const float L2 = lane0 ? bprev : l2s;  // c[r-1][col-1]
            float m0 = fminf(fminf(cur0, L1), L2);
            if (r0row) m0 = (lane0 && g == 0) ? 0.f : L1;  // row 0: left only
            const float c0 = e0 + m0;
            float m1 = fminf(fminf(cur1, c0), cur0);
            if (r0row) m1 = c0;
            const float c1 = e1 + m1;
            cur0 = c0; cur1 = c1;

            if (pub && (unsigned)rl < (unsigned)NN)
                __hip_atomic_store(colMu + rl, __float_as_uint(c1),
                                   __ATOMIC_RELAXED, __HIP_MEMORY_SCOPE_AGENT);
            if (last && rl == NN - 1) cost_out[0] = c1;

            const float sh = dpp_wave_shr1(c1);    // to lane l+1 next step
            l2s = l1s; l1s = sh;
            bprev = bcur;
            rl += 1;
            raddr += SW * 4;
            if (raddr >= RING_BYTES) raddr -= RING_BYTES;
        }
    }
}

// ---------------------------------------------------------------------------
// acc_grad[i,j] = d[i+1,j+1] + d[i+1,j] + d[i,j+1] - d[i,j],  d = exp(-exp(-D))
// (zero-padded bottom/right). Unchanged from round 1 (passed, ~20us).
// ---------------------------------------------------------------------------
__device__ __forceinline__ float dfun(float x) { return __expf(-__expf(-x)); }

__global__ __launch_bounds__(256) void dtw_grad_kernel(const float* __restrict__ D,
                                                       float* __restrict__ G) {
    const int idx = blockIdx.x * 256 + threadIdx.x;
    const int i = idx >> 10;
    const int j = (idx & 1023) << 2;
    if (i >= NN) return;

    const float* row0 = D + (size_t)i * NN + j;
    const bool hasR = (i + 1) < NN;
    const bool hasC = (j + 4) < NN;

    const float4 r0 = *reinterpret_cast<const float4*>(row0);
    float4 r1 = make_float4(0.f, 0.f, 0.f, 0.f);
    if (hasR) r1 = *reinterpret_cast<const float4*>(row0 + NN);
    const float s0 = hasC ? row0[4] : 0.f;
    const float s1 = (hasR && hasC) ? row0[NN + 4] : 0.f;

    const float a0 = dfun(r0.x), a1 = dfun(r0.y), a2 = dfun(r0.z), a3 = dfun(r0.w);
    const float a4 = hasC ? dfun(s0) : 0.f;
    const float b0 = hasR ? dfun(r1.x) : 0.f;
    const float b1 = hasR ? dfun(r1.y) : 0.f;
    const float b2 = hasR ? dfun(r1.z) : 0.f;
    const float b3 = hasR ? dfun(r1.w) : 0.f;
    const float b4 = (hasR && hasC) ? dfun(s1) : 0.f;

    float* go = G + (size_t)i * NN + j;
    go[0] = b1 + b0 + a1 - a0;
    go[1] = b2 + b1 + a2 - a1;
    go[2] = b3 + b2 + a3 - a2;
    go[3] = b4 + b3 + a4 - a3;
}

// ---------------------------------------------------------------------------
extern "C" void kernel_launch(void* const* d_in, const int* in_sizes, int n_in,
                              void* d_out, int out_size, void* d_ws, size_t ws_size,
                              hipStream_t stream) {
    (void)in_sizes; (void)n_in; (void)out_size;
    const float* D = (const float*)d_in[0];
    float* out = (float*)d_out;

    const size_t need = (size_t)STRIPS * NN * sizeof(unsigned);
    unsigned* colbuf = (ws_size >= need) ? (unsigned*)d_ws : (unsigned*)(out + 1);

    // sentinel-fill boundary buffer (sync is "value != 0xFFFFFFFF")
    hipMemsetAsync(colbuf, 0xFF, need, stream);
    dtw_dp<<<STRIPS, 64, 0, stream>>>(D, out, colbuf);
    dtw_grad_kernel<<<dim3((NN * (NN / 4)) / 256), dim3(256), 0, stream>>>(D, out + 1);
}